// Round 3
// baseline (183.156 us; speedup 1.0000x reference)
//
#include <hip/hip_runtime.h>
#include <math.h>

// DiffKS round 6.
// Kernel A (parallel): unchanged.
// Kernel B (1 wave), phase 2 restructured around the round-5 finding:
//   VGPR_Count=132 proves the compiler never materialized the 8-body CFq
//   register ring (needs ~190 VGPRs) — the coefficient global loads were
//   sunk/spilled onto the serial chain (~560 cy/body stall ≈ VMEM latency).
//   Round 6 removes ALL VMEM from the body loop:
//   * coefficients double-buffer-staged per 8-body group into LDS via
//     __builtin_amdgcn_global_load_lds (25 x 1KB async issues/group; ws is
//     already t-ordered so the linear LDS dest needs no swizzle),
//   * one explicit s_waitcnt vmcnt(0) per group (between bodies 5 and 6),
//   * per-body coefficients from LDS through a depth-4 register ring
//     (64 VGPRs, literal indexing, loaded 2 bodies ahead),
//   * serial chain is now only: 7-FMA chain -> ds_write -> history ds_read.
//   FMA order per sample is bit-identical to round 5 (absmax at threshold).

#define T_SAMPLES 44100
#define NFRAMES   100
#define NCOEF     6
#define NACT      7
#define BURST     2048
#define EXC_ORD   5

#define C2        100           // samples per body
#define HISTSZ    1096          // 1024 ring + 7 mirror + 1 + 64 dump slots
#define CFPAD     6528          // 6400 floats/group + pad for lane>=50 reads

#define WS_COEF_FLOATS (T_SAMPLES * 8)
#define WS_EXC_OFF     WS_COEF_FLOATS
#define WS_EXC_FLOATS  (EXC_ORD * BURST)
#define WS_TOTAL_BYTES ((size_t)(WS_COEF_FLOATS + WS_EXC_FLOATS) * 4)

// ---------------------------------------------------------------- kernel A
__global__ __launch_bounds__(256) void diffks_precompute(
    const float* __restrict__ delay_frames,
    const float* __restrict__ raw_coeff,
    const float* __restrict__ raw_gain,
    const float* __restrict__ exc_coeff,
    float* __restrict__ ws)
{
    int g = blockIdx.x * 256 + threadIdx.x;
    const float gain = 0.1f / (1.0f + expf(-raw_gain[0])) + 0.9f;

    if (g < T_SAMPLES) {
        const float stepT = 99.0f / (float)(T_SAMPLES - 1);
        float pos = (float)g * stepT;
        int i0 = (int)pos; if (i0 > NFRAMES - 2) i0 = NFRAMES - 2;
        float w = pos - (float)i0;

        float d0 = delay_frames[i0], d1 = delay_frames[i0 + 1];
        float delay = d0 + (d1 - d0) * w;
        int z = (int)delay;                  // delay >= 100 > 0
        float alfa = delay - (float)z;

        float b[NCOEF];
        {
            float c0v[NCOEF], c1v[NCOEF];
            float s0 = 0.f, s1 = 0.f;
            #pragma unroll
            for (int j = 0; j < NCOEF; ++j) {
                c0v[j] = 1.0f / (1.0f + expf(-raw_coeff[i0 * NCOEF + j]));
                c1v[j] = 1.0f / (1.0f + expf(-raw_coeff[(i0 + 1) * NCOEF + j]));
                s0 += c0v[j]; s1 += c1v[j];
            }
            float g0 = gain / s0, g1 = gain / s1;
            #pragma unroll
            for (int j = 0; j < NCOEF; ++j) {
                float x0 = c0v[j] * g0, x1 = c1v[j] * g1;
                b[j] = x0 + (x1 - x0) * w;
            }
        }
        float oma = 1.0f - alfa;
        float v0 = -oma * b[0];
        float v1 = -(alfa * b[0] + oma * b[1]);
        float v2 = -(alfa * b[1] + oma * b[2]);
        float v3 = -(alfa * b[2] + oma * b[3]);
        float v4 = -(alfa * b[3] + oma * b[4]);
        float v5 = -(alfa * b[4] + oma * b[5]);
        float v6 = -alfa * b[5];
        int base = g - z - 1;

        float4* o = (float4*)(ws + (size_t)g * 8);
        o[0] = make_float4(v0, v1, v2, v3);
        o[1] = make_float4(v4, v5, v6, __int_as_float(base));
    } else if (g < T_SAMPLES + BURST) {
        int te = g - T_SAMPLES;
        const float stepE = 99.0f / (float)(BURST - 1);
        float pos = (float)te * stepE;
        int i0 = (int)pos; if (i0 > NFRAMES - 2) i0 = NFRAMES - 2;
        float w = pos - (float)i0;
        float* o = ws + WS_EXC_OFF + te * EXC_ORD;     // interleaved [t*5+k]
        #pragma unroll
        for (int k = 0; k < EXC_ORD; ++k) {
            float a0 = exc_coeff[i0 * EXC_ORD + k];
            float a1 = exc_coeff[(i0 + 1) * EXC_ORD + k];
            o[k] = a0 + (a1 - a0) * w;
        }
    }
}

// async global->LDS copy, 16B per lane; LDS base must be wave-uniform
__device__ __forceinline__ void gload_lds16(const float* g, float* l) {
    __builtin_amdgcn_global_load_lds(
        (const __attribute__((address_space(1))) unsigned int*)(g),
        (__attribute__((address_space(3))) unsigned int*)(l),
        16, 0, 0);
}

// ---------------------------------------------------------------- kernel B
__global__ __launch_bounds__(64, 1) void diffks_serial(
    const float* __restrict__ excitation,
    const float* __restrict__ ws,
    float* __restrict__ out)
{
    __shared__ float s_cf[2][CFPAD];     // coefficient double buffer (t-order)
    __shared__ float s_x[64][33];        // burst (padded rows)
    __shared__ float s_a[64][161];       // exc coefs [seg][(i%32)*5+k]
    __shared__ float s_hist[HISTSZ];     // 1024 ring + 7 mirror + 64 dump
    __shared__ float s_tail[64][32];
    __shared__ float s_bound[64][6];

    const int lane = threadIdx.x;

    // ---- stage ----
    for (int t = lane; t < BURST; t += 64)
        s_x[t >> 5][t & 31] = excitation[t];
    {   // exc coefs: lane handles t = lane + 64*i, 5 contiguous scalars each
        for (int i = 0; i < 32; ++i) {
            int t = lane + i * 64;
            const float* g = ws + WS_EXC_OFF + t * EXC_ORD;
            float* dst = &s_a[t >> 5][(t & 31) * 5];
            dst[0] = g[0]; dst[1] = g[1]; dst[2] = g[2];
            dst[3] = g[3]; dst[4] = g[4];
        }
    }
    for (int i = lane; i < HISTSZ; i += 64) s_hist[i] = 0.0f;
    __syncthreads();

    // ---- phase 1: excitation LPC via 64-segment state-space scan ----
    {
        float st[6][5];
        #pragma unroll
        for (int r = 0; r < 6; ++r)
            #pragma unroll
            for (int k = 0; k < 5; ++k) st[r][k] = 0.0f;
        #pragma unroll
        for (int r = 1; r <= 5; ++r) st[r][r - 1] = 1.0f;

        const float* ar = &s_a[lane][0];
        const float* xr = &s_x[lane][0];
        #pragma unroll 8
        for (int i = 0; i < 32; ++i) {
            float a0 = ar[i * 5 + 0], a1 = ar[i * 5 + 1], a2 = ar[i * 5 + 2];
            float a3 = ar[i * 5 + 3], a4 = ar[i * 5 + 4];
            float xv = xr[i];
            #pragma unroll
            for (int r = 0; r < 6; ++r) {
                float acc = (r == 0) ? xv : 0.0f;
                acc = fmaf(-a0, st[r][0], acc);
                acc = fmaf(-a1, st[r][1], acc);
                acc = fmaf(-a2, st[r][2], acc);
                acc = fmaf(-a3, st[r][3], acc);
                acc = fmaf(-a4, st[r][4], acc);
                st[r][4] = st[r][3]; st[r][3] = st[r][2];
                st[r][2] = st[r][1]; st[r][1] = st[r][0];
                st[r][0] = acc;
            }
        }
        #pragma unroll
        for (int r = 0; r < 6; ++r)
            #pragma unroll
            for (int k = 0; k < 5; ++k)
                s_tail[lane][r * 5 + k] = st[r][k];
    }
    __syncthreads();

    if (lane == 0) {   // chain 5-dim boundary states through 64 segments
        float Y[5] = {0.f, 0.f, 0.f, 0.f, 0.f};
        for (int l = 0; l < 64; ++l) {
            #pragma unroll
            for (int c = 0; c < 5; ++c) s_bound[l][c] = Y[c];
            float tl[30];
            #pragma unroll
            for (int j = 0; j < 30; ++j) tl[j] = s_tail[l][j];
            float ny[5];
            #pragma unroll
            for (int k = 0; k < 5; ++k) {
                float acc = tl[k];
                #pragma unroll
                for (int c = 1; c <= 5; ++c)
                    acc = fmaf(tl[c * 5 + k], Y[c - 1], acc);
                ny[k] = acc;
            }
            #pragma unroll
            for (int k = 0; k < 5; ++k) Y[k] = ny[k];
        }
    }
    __syncthreads();

    {   // re-run each segment with correct boundary state
        float b0 = s_bound[lane][0], b1 = s_bound[lane][1], b2 = s_bound[lane][2];
        float b3 = s_bound[lane][3], b4 = s_bound[lane][4];
        const float* ar = &s_a[lane][0];
        float* xr = &s_x[lane][0];
        #pragma unroll 8
        for (int i = 0; i < 32; ++i) {
            float a0 = ar[i * 5 + 0], a1 = ar[i * 5 + 1], a2 = ar[i * 5 + 2];
            float a3 = ar[i * 5 + 3], a4 = ar[i * 5 + 4];
            float acc = xr[i];
            acc = fmaf(-a0, b0, acc);
            acc = fmaf(-a1, b1, acc);
            acc = fmaf(-a2, b2, acc);
            acc = fmaf(-a3, b3, acc);
            acc = fmaf(-a4, b4, acc);
            b4 = b3; b3 = b2; b2 = b1; b1 = b0; b0 = acc;
            xr[i] = acc;
        }
    }
    __syncthreads();

    // ---- phase 2: barrier-free resonator, C=100, 2 samples/lane ----
    const bool lane_act = (lane < 50);
    const unsigned dumpA = 1032u + (unsigned)lane;   // per-lane dump slot

    // stage coefficients for group gg into s_cf[gg&1] (async, vmcnt-tracked)
    #define STAGE_GRP(gg)                                                      \
    {                                                                          \
        float* dstb = s_cf[(gg) & 1];                                          \
        const float* srcb = ws + (size_t)(gg) * 6400 + lane * 4;               \
        const int nis = ((gg) == 55) ? 4 : 25;                                 \
        for (int i = 0; i < nis; ++i)                                          \
            gload_lds16(srcb + i * 256, dstb + i * 256);                       \
    }

    // prologue: stage group 0, wait, fill coef ring slots 0,1
    STAGE_GRP(0)
    asm volatile("s_waitcnt vmcnt(0)" ::: "memory");

    // coef ring: depth 4, slot j = cc&3. [0],[1] = sample A, [2],[3] = sample B
    float4 CF4[4][4];
    {
        const float4* cfp = (const float4*)s_cf[0];
        #pragma unroll
        for (int b = 0; b < 2; ++b) {
            int lb = b * 100 + lane;
            CF4[b][0] = cfp[lb * 2 + 0];
            CF4[b][1] = cfp[lb * 2 + 1];
            CF4[b][2] = cfp[(lb + 50) * 2 + 0];
            CF4[b][3] = cfp[(lb + 50) * 2 + 1];
        }
    }

    // hu[parity][sample][k]: history y[base-6+k]; body 0's history all zero
    float hu[2][2][7];
    #pragma unroll
    for (int k = 0; k < 7; ++k) {
        hu[0][0][k] = 0.f; hu[0][1][k] = 0.f;
        hu[1][0][k] = 0.f; hu[1][1][k] = 0.f;
    }

    // Body j of current group (cc = cb + j, cb = g*8):
    //  1. 14 FMAs (two independent 7-chains) from CF4[j&3], hu[j&1]
    //  2. branchless LDS writes (ring + mirror, inactive lanes -> dump)
    //  3. history reads for body cc+1 (bases in CF4[(j+1)&3]) -> hu[(j&1)^1]
    //  4. coef LDS->reg prefetch for body cc+2 into CF4[(j+2)&3]
    //     (bodies j=6,7 read the NEXT group's buffer cfn)
    #define KS3_BODY(j, WITHX, DO_NEXT)                                        \
    {                                                                          \
        const float4 a0 = CF4[(j) & 3][0], a1 = CF4[(j) & 3][1];               \
        const float4 b0 = CF4[(j) & 3][2], b1 = CF4[(j) & 3][3];               \
        const int tA = cb100 + (j) * 100 + lane;                               \
        const int tB = tA + 50;                                                \
        float accA, accB;                                                      \
        if (WITHX) {                                                           \
            accA = (lane_act && tA < BURST) ? s_x[tA >> 5][tA & 31] : 0.0f;    \
            accB = (lane_act && tB < BURST) ? s_x[tB >> 5][tB & 31] : 0.0f;    \
        } else { accA = 0.0f; accB = 0.0f; }                                   \
        accA = fmaf(-a0.x, hu[(j) & 1][0][6], accA);                           \
        accB = fmaf(-b0.x, hu[(j) & 1][1][6], accB);                           \
        accA = fmaf(-a0.y, hu[(j) & 1][0][5], accA);                           \
        accB = fmaf(-b0.y, hu[(j) & 1][1][5], accB);                           \
        accA = fmaf(-a0.z, hu[(j) & 1][0][4], accA);                           \
        accB = fmaf(-b0.z, hu[(j) & 1][1][4], accB);                           \
        accA = fmaf(-a0.w, hu[(j) & 1][0][3], accA);                           \
        accB = fmaf(-b0.w, hu[(j) & 1][1][3], accB);                           \
        accA = fmaf(-a1.x, hu[(j) & 1][0][2], accA);                           \
        accB = fmaf(-b1.x, hu[(j) & 1][1][2], accB);                           \
        accA = fmaf(-a1.y, hu[(j) & 1][0][1], accA);                           \
        accB = fmaf(-b1.y, hu[(j) & 1][1][1], accB);                           \
        accA = fmaf(-a1.z, hu[(j) & 1][0][0], accA);                           \
        accB = fmaf(-b1.z, hu[(j) & 1][1][0], accB);                           \
        const unsigned pA = ((unsigned)tA) & 1023u;                            \
        const unsigned pB = ((unsigned)tB) & 1023u;                            \
        s_hist[lane_act ? pA : dumpA] = accA;                                  \
        s_hist[lane_act ? pB : dumpA] = accB;                                  \
        s_hist[(lane_act && pA < 7u) ? (pA + 1024u) : dumpA] = accA;           \
        s_hist[(lane_act && pB < 7u) ? (pB + 1024u) : dumpA] = accB;           \
        if (DO_NEXT) {                                                         \
            int nbA = __float_as_int(CF4[((j) + 1) & 3][1].w);                 \
            int nbB = __float_as_int(CF4[((j) + 1) & 3][3].w);                 \
            unsigned qA = ((unsigned)(nbA - 6)) & 1023u;                       \
            unsigned qB = ((unsigned)(nbB - 6)) & 1023u;                       \
            const float* hbA = &s_hist[qA];                                    \
            const float* hbB = &s_hist[qB];                                    \
            hu[((j) & 1) ^ 1][0][0] = hbA[0];                                  \
            hu[((j) & 1) ^ 1][0][1] = hbA[1];                                  \
            hu[((j) & 1) ^ 1][0][2] = hbA[2];                                  \
            hu[((j) & 1) ^ 1][0][3] = hbA[3];                                  \
            hu[((j) & 1) ^ 1][0][4] = hbA[4];                                  \
            hu[((j) & 1) ^ 1][0][5] = hbA[5];                                  \
            hu[((j) & 1) ^ 1][0][6] = hbA[6];                                  \
            hu[((j) & 1) ^ 1][1][0] = hbB[0];                                  \
            hu[((j) & 1) ^ 1][1][1] = hbB[1];                                  \
            hu[((j) & 1) ^ 1][1][2] = hbB[2];                                  \
            hu[((j) & 1) ^ 1][1][3] = hbB[3];                                  \
            hu[((j) & 1) ^ 1][1][4] = hbB[4];                                  \
            hu[((j) & 1) ^ 1][1][5] = hbB[5];                                  \
            hu[((j) & 1) ^ 1][1][6] = hbB[6];                                  \
            {                                                                  \
                const float4* cfp =                                            \
                    (const float4*)(((j) + 2 < 8) ? cfc : cfn);                \
                const int lb = (((j) + 2) & 7) * 100 + lane;                   \
                CF4[((j) + 2) & 3][0] = cfp[lb * 2 + 0];                       \
                CF4[((j) + 2) & 3][1] = cfp[lb * 2 + 1];                       \
                CF4[((j) + 2) & 3][2] = cfp[(lb + 50) * 2 + 0];                \
                CF4[((j) + 2) & 3][3] = cfp[(lb + 50) * 2 + 1];                \
            }                                                                  \
        }                                                                      \
    }

    // dump 800 samples of group g from the ring (coalesced, off-chain)
    #define DUMP800(g)                                                         \
    {                                                                          \
        const int t0 = (g) * 800;                                              \
        _Pragma("unroll")                                                      \
        for (int i = 0; i < 12; ++i) {                                         \
            int t = t0 + i * 64 + lane;                                        \
            out[t] = s_hist[((unsigned)t) & 1023u];                            \
        }                                                                      \
        {                                                                      \
            int t = t0 + 768 + lane;                                           \
            if (lane < 32) out[t] = s_hist[((unsigned)t) & 1023u];             \
        }                                                                      \
    }

    // groups 0..2 (bodies 0..23): excitation mix active (t < 2400 covers 2048)
    #pragma unroll 1
    for (int g = 0; g < 3; ++g) {
        float* cfc = s_cf[g & 1];
        float* cfn = s_cf[(g & 1) ^ 1];
        const int cb100 = g * 800;
        KS3_BODY(0, true, true)
        STAGE_GRP(g + 1)
        KS3_BODY(1, true, true)
        KS3_BODY(2, true, true)
        KS3_BODY(3, true, true)
        KS3_BODY(4, true, true)
        KS3_BODY(5, true, true)
        asm volatile("s_waitcnt vmcnt(0)" ::: "memory");
        KS3_BODY(6, true, true)
        KS3_BODY(7, true, true)
        DUMP800(g)
    }
    // groups 3..54 (bodies 24..439): steady state
    #pragma unroll 1
    for (int g = 3; g < 55; ++g) {
        float* cfc = s_cf[g & 1];
        float* cfn = s_cf[(g & 1) ^ 1];
        const int cb100 = g * 800;
        KS3_BODY(0, false, true)
        STAGE_GRP(g + 1)
        KS3_BODY(1, false, true)
        KS3_BODY(2, false, true)
        KS3_BODY(3, false, true)
        KS3_BODY(4, false, true)
        KS3_BODY(5, false, true)
        asm volatile("s_waitcnt vmcnt(0)" ::: "memory");
        KS3_BODY(6, false, true)
        KS3_BODY(7, false, true)
        DUMP800(g)
    }
    // tail body 440 (slot 0, parity 0; hu loaded by body 439, CF4[0] by 438)
    {
        float* cfc = s_cf[1];
        float* cfn = s_cf[0];
        const int cb100 = 44000;
        (void)cfc; (void)cfn;
        KS3_BODY(0, false, false)
    }
    // final dump: t in [44000, 44100)
    {
        int t = 44000 + lane;
        out[t] = s_hist[((unsigned)t) & 1023u];
        int t2 = t + 64;
        if (lane < 36) out[t2] = s_hist[((unsigned)t2) & 1023u];
    }
    #undef KS3_BODY
    #undef DUMP800
    #undef STAGE_GRP
}

// ------------------------------------------------- fallback (round-1 kernel)
#define CHUNK_FB  101
#define NCH_FB    ((T_SAMPLES + CHUNK_FB - 1) / CHUNK_FB)
#define HIST_FB   1024

__global__ __launch_bounds__(128) void diffks_fallback(
    const float* __restrict__ delay_frames,
    const float* __restrict__ excitation,
    const float* __restrict__ raw_coeff,
    const float* __restrict__ raw_gain,
    const float* __restrict__ exc_coeff,
    float* __restrict__ out)
{
    __shared__ float s_a[EXC_ORD][BURST];
    __shared__ float s_x[BURST];
    __shared__ float s_hist[HIST_FB];
    __shared__ __align__(16) float s_coef[NFRAMES][8];
    __shared__ float s_delay[NFRAMES];

    const int tid = threadIdx.x;
    const float gain = 0.1f / (1.0f + expf(-raw_gain[0])) + 0.9f;

    for (int i = tid; i < NFRAMES; i += 128) s_delay[i] = delay_frames[i];
    for (int f = tid; f < NFRAMES; f += 128) {
        float sb[NCOEF]; float s = 0.0f;
        #pragma unroll
        for (int j = 0; j < NCOEF; ++j) {
            sb[j] = 1.0f / (1.0f + expf(-raw_coeff[f * NCOEF + j]));
            s += sb[j];
        }
        float inv = gain / s;
        #pragma unroll
        for (int j = 0; j < NCOEF; ++j) s_coef[f][j] = sb[j] * inv;
        s_coef[f][6] = 0.0f; s_coef[f][7] = 0.0f;
    }
    const float stepE = 99.0f / 2047.0f;
    for (int t = tid; t < BURST; t += 128) {
        float pos = (float)t * stepE;
        int i0 = (int)pos; if (i0 > NFRAMES - 2) i0 = NFRAMES - 2;
        float w = pos - (float)i0;
        const float* c0 = exc_coeff + i0 * EXC_ORD;
        #pragma unroll
        for (int k = 0; k < EXC_ORD; ++k) {
            float a0 = c0[k], a1 = c0[k + EXC_ORD];
            s_a[k][t] = a0 + (a1 - a0) * w;
        }
        s_x[t] = excitation[t];
    }
    for (int i = tid; i < HIST_FB; i += 128) s_hist[i] = 0.0f;
    __syncthreads();

    if (tid == 0) {
        float y1 = 0.f, y2 = 0.f, y3 = 0.f, y4 = 0.f, y5 = 0.f;
        #pragma unroll 4
        for (int t = 0; t < BURST; ++t) {
            float p = s_x[t];
            p = fmaf(-s_a[1][t], y2, p);
            p = fmaf(-s_a[2][t], y3, p);
            p = fmaf(-s_a[3][t], y4, p);
            p = fmaf(-s_a[4][t], y5, p);
            float y = fmaf(-s_a[0][t], y1, p);
            s_x[t] = y;
            y5 = y4; y4 = y3; y3 = y2; y2 = y1; y1 = y;
        }
    }
    __syncthreads();

    const float stepT = 99.0f / (float)(T_SAMPLES - 1);
    for (int c = 0; c < NCH_FB; ++c) {
        int t = c * CHUNK_FB + tid;
        if (tid < CHUNK_FB && t < T_SAMPLES) {
            float pos = (float)t * stepT;
            int i0 = (int)pos; if (i0 > NFRAMES - 2) i0 = NFRAMES - 2;
            float w = pos - (float)i0;
            float d0 = s_delay[i0], d1 = s_delay[i0 + 1];
            float delay = d0 + (d1 - d0) * w;
            int z = (int)delay;
            float alfa = delay - (float)z;
            const float4* f0 = reinterpret_cast<const float4*>(s_coef[i0]);
            const float4* f1 = reinterpret_cast<const float4*>(s_coef[i0 + 1]);
            float4 c0a = f0[0], c0b = f0[1];
            float4 c1a = f1[0], c1b = f1[1];
            float b[NCOEF];
            b[0] = c0a.x + (c1a.x - c0a.x) * w;
            b[1] = c0a.y + (c1a.y - c0a.y) * w;
            b[2] = c0a.z + (c1a.z - c0a.z) * w;
            b[3] = c0a.w + (c1a.w - c0a.w) * w;
            b[4] = c0b.x + (c1b.x - c0b.x) * w;
            b[5] = c0b.y + (c1b.y - c0b.y) * w;
            float oma = 1.0f - alfa;
            float v[NACT];
            v[0] = -oma * b[0];
            #pragma unroll
            for (int j = 1; j <= 5; ++j) v[j] = -(alfa * b[j - 1] + oma * b[j]);
            v[6] = -alfa * b[5];
            float x = (t < BURST) ? s_x[t] : 0.0f;
            int base = t - z - 1;
            float sum = 0.0f;
            #pragma unroll
            for (int j = 0; j < NACT; ++j) {
                int idx = base - j;
                float yv = s_hist[idx & (HIST_FB - 1)];
                if (idx < 0) yv = 0.0f;
                sum = fmaf(v[j], yv, sum);
            }
            float y = x - sum;
            s_hist[t & (HIST_FB - 1)] = y;
            out[t] = y;
        }
        __syncthreads();
    }
}

// ---------------------------------------------------------------- launch
extern "C" void kernel_launch(void* const* d_in, const int* in_sizes, int n_in,
                              void* d_out, int out_size, void* d_ws, size_t ws_size,
                              hipStream_t stream) {
    const float* delay_frames = (const float*)d_in[0];
    const float* excitation   = (const float*)d_in[1];
    const float* raw_coeff    = (const float*)d_in[2];
    const float* raw_gain     = (const float*)d_in[3];
    const float* exc_coeff    = (const float*)d_in[4];
    float* out = (float*)d_out;

    if (ws_size >= WS_TOTAL_BYTES) {
        float* ws = (float*)d_ws;
        int gridA = (T_SAMPLES + BURST + 255) / 256;
        diffks_precompute<<<gridA, 256, 0, stream>>>(delay_frames, raw_coeff,
                                                     raw_gain, exc_coeff, ws);
        diffks_serial<<<1, 64, 0, stream>>>(excitation, ws, out);
    } else {
        diffks_fallback<<<1, 128, 0, stream>>>(delay_frames, excitation,
                                               raw_coeff, raw_gain, exc_coeff, out);
    }
}